// Round 6
// baseline (266.678 us; speedup 1.0000x reference)
//
#include <hip/hip_runtime.h>
#include <float.h>

using v2f = __attribute__((ext_vector_type(2))) float;
using v4f = __attribute__((ext_vector_type(4))) float;

#define EMB 10
#define STATE 20
#define HIDDEN 40
#define NPROJ 2490
#define NSPLIT 4                 // row-split waves per 64-element block

// Per-element MLP: x = [wemb[wi], pemb[pi]] -> relu(W1 x + b1) -> W2 h + b2
__device__ __forceinline__ void mlp_eval(
    const float* __restrict__ wr, const float* __restrict__ pr,
    const float* __restrict__ W1, const float* __restrict__ b1,
    const float* __restrict__ W2, const float* __restrict__ b2,
    v2f wv2[5])
{
    v2f x2[STATE / 2];
    #pragma unroll
    for (int k = 0; k < EMB / 2; ++k) x2[k] = *(const v2f*)(wr + 2 * k);
    #pragma unroll
    for (int k = 0; k < EMB / 2; ++k) x2[EMB / 2 + k] = *(const v2f*)(pr + 2 * k);

    float hb[HIDDEN];
    #pragma unroll 4
    for (int j = 0; j < HIDDEN; ++j) {       // W1/b1 uniform -> scalar loads
        const v2f* w1r = (const v2f*)(W1 + j * STATE);
        v2f a = w1r[0] * x2[0];
        #pragma unroll
        for (int k = 1; k < STATE / 2; ++k) a += w1r[k] * x2[k];
        hb[j] = fmaxf(a.x + a.y + b1[j], 0.0f);
    }
    v2f h2[HIDDEN / 2];
    #pragma unroll
    for (int k = 0; k < HIDDEN / 2; ++k) h2[k] = (v2f){hb[2 * k], hb[2 * k + 1]};

    #pragma unroll
    for (int d = 0; d < EMB; d += 2) {
        const v2f* w2r0 = (const v2f*)(W2 + d * HIDDEN);
        const v2f* w2r1 = (const v2f*)(W2 + (d + 1) * HIDDEN);
        v2f a0 = w2r0[0] * h2[0];
        v2f a1 = w2r1[0] * h2[0];
        #pragma unroll
        for (int k = 1; k < HIDDEN / 2; ++k) { a0 += w2r0[k] * h2[k]; a1 += w2r1[k] * h2[k]; }
        wv2[d / 2] = (v2f){a0.x + a0.y + b2[d], a1.x + a1.y + b2[d + 1]};
    }
}

// Single row score (for the lone row 1)
__device__ __forceinline__ float dot_row(const float* __restrict__ row, const v2f wv[5]) {
    v2f c0 = *(const v2f*)(row + 0);
    v4f c1 = *(const v4f*)(row + 2);
    v4f c2 = *(const v4f*)(row + 6);
    v2f a = wv[0] * c0;
    a += wv[1] * c1.lo; a += wv[2] * c1.hi;
    a += wv[3] * c2.lo; a += wv[4] * c2.hi;
    return a.x + a.y;
}

// One even row-pair (rows 2p, 2p+1), ONE element's weights (R3-proven body).
// tbl4 indexed only by uniform p -> s_load_dwordx4 (SGPR data, wave-uniform).
__device__ __forceinline__ void score_pair(const v4f* __restrict__ tbl4, int p,
                                           const v2f wv2[5],
                                           float& best, int& bidx) {
    const v4f* tp = tbl4 + p * 5;
    v4f a0 = tp[0], a1 = tp[1], a2 = tp[2], a3 = tp[3], a4 = tp[4];
    v2f c0 = wv2[0] * a0.lo;
    c0 += wv2[1] * a0.hi; c0 += wv2[2] * a1.lo;
    c0 += wv2[3] * a1.hi; c0 += wv2[4] * a2.lo;
    float s0 = c0.x + c0.y;
    v2f c1 = wv2[0] * a2.hi;
    c1 += wv2[1] * a3.lo; c1 += wv2[2] * a3.hi;
    c1 += wv2[3] * a4.lo; c1 += wv2[4] * a4.hi;
    float s1 = c1.x + c1.y;
    float sp = s0; int ip = 2 * p;
    if (s1 > sp) { sp = s1; ip = 2 * p + 1; }   // strict > : earlier index wins ties
    if (sp > best) { best = sp; bidx = ip; }
}

__global__ __launch_bounds__(256, 4) void actor_kernel(
    const int* __restrict__ wid, const int* __restrict__ pid,
    const float* __restrict__ wemb, const float* __restrict__ pemb,
    const float* __restrict__ W1, const float* __restrict__ b1,
    const float* __restrict__ W2, const float* __restrict__ b2,
    int* __restrict__ out)
{
    __shared__ float sb[NSPLIT][64];
    __shared__ int   si[NSPLIT][64];

    const int tid  = threadIdx.x;
    const int lane = tid & 63;
    const int h    = tid >> 6;             // row-split worker 0..3
    const int b    = blockIdx.x * 64 + lane;

    const v4f* __restrict__ tbl4 = (const v4f*)__builtin_assume_aligned(pemb, 16);

    // ---- MLP (computed redundantly by all 4 waves; lane-identical inputs) ----
    v2f wv2[5];
    mlp_eval(wemb + wid[b] * EMB, pemb + pid[b] * EMB, W1, b1, W2, b2, wv2);

    float best = -FLT_MAX;
    int   bidx = 1;

    // FULL pair range [1,1245) = rows 2..2489, split 4 ways; lone row 1 -> h0.
    const int plo[NSPLIT + 1] = {1, 312, 623, 934, 1245};
    if (h == 0) { best = dot_row(pemb + 10, wv2); bidx = 1; }
    const int lo = plo[h], hi = plo[h + 1];
    #pragma unroll 4
    for (int p = lo; p < hi; ++p)
        score_pair(tbl4, p, wv2, best, bidx);

    // ---- combine the 4 row-chunks (ascending index ranges -> strict > exact) ----
    sb[h][lane] = best;
    si[h][lane] = bidx;
    __syncthreads();
    if (h == 0) {
        #pragma unroll
        for (int k = 1; k < NSPLIT; ++k) {
            float v = sb[k][lane]; int j = si[k][lane];
            if (v > best) { best = v; bidx = j; }
        }
        out[b] = bidx;
    }
}

extern "C" void kernel_launch(void* const* d_in, const int* in_sizes, int n_in,
                              void* d_out, int out_size, void* d_ws, size_t ws_size,
                              hipStream_t stream) {
    const int*   wid  = (const int*)  d_in[0];
    const int*   pid  = (const int*)  d_in[1];
    const float* wemb = (const float*)d_in[2];
    const float* pemb = (const float*)d_in[3];
    const float* W1   = (const float*)d_in[4];
    const float* b1   = (const float*)d_in[5];
    const float* W2   = (const float*)d_in[6];
    const float* b2   = (const float*)d_in[7];
    int* out = (int*)d_out;

    const int B = in_sizes[0];               // 65536
    actor_kernel<<<B / 64, 256, 0, stream>>>(wid, pid, wemb, pemb, W1, b1, W2, b2, out);
}

// Round 7
// 252.196 us; speedup vs baseline: 1.0574x; 1.0574x over previous
//
#include <hip/hip_runtime.h>
#include <float.h>

using v2f = __attribute__((ext_vector_type(2))) float;
using v4f = __attribute__((ext_vector_type(4))) float;

#define EMB 10
#define STATE 20
#define HIDDEN 40
#define NPROJ 2490

// Per-element MLP: x = [wemb[wi], pemb[pi]] -> relu(W1 x + b1) -> W2 h + b2
// (weights are block-uniform -> compiler scalarizes them to s_loads; proven R3 path)
__device__ __forceinline__ void mlp_eval(
    const float* __restrict__ wr, const float* __restrict__ pr,
    const float* __restrict__ W1, const float* __restrict__ b1,
    const float* __restrict__ W2, const float* __restrict__ b2,
    v2f wv2[5])
{
    v2f x2[STATE / 2];
    #pragma unroll
    for (int k = 0; k < EMB / 2; ++k) x2[k] = *(const v2f*)(wr + 2 * k);
    #pragma unroll
    for (int k = 0; k < EMB / 2; ++k) x2[EMB / 2 + k] = *(const v2f*)(pr + 2 * k);

    float hb[HIDDEN];
    #pragma unroll 4
    for (int j = 0; j < HIDDEN; ++j) {
        const v2f* w1r = (const v2f*)(W1 + j * STATE);
        v2f a = w1r[0] * x2[0];
        #pragma unroll
        for (int k = 1; k < STATE / 2; ++k) a += w1r[k] * x2[k];
        hb[j] = fmaxf(a.x + a.y + b1[j], 0.0f);
    }
    v2f h2[HIDDEN / 2];
    #pragma unroll
    for (int k = 0; k < HIDDEN / 2; ++k) h2[k] = (v2f){hb[2 * k], hb[2 * k + 1]};

    #pragma unroll
    for (int d = 0; d < EMB; d += 2) {
        const v2f* w2r0 = (const v2f*)(W2 + d * HIDDEN);
        const v2f* w2r1 = (const v2f*)(W2 + (d + 1) * HIDDEN);
        v2f a0 = w2r0[0] * h2[0];
        v2f a1 = w2r1[0] * h2[0];
        #pragma unroll
        for (int k = 1; k < HIDDEN / 2; ++k) { a0 += w2r0[k] * h2[k]; a1 += w2r1[k] * h2[k]; }
        wv2[d / 2] = (v2f){a0.x + a0.y + b2[d], a1.x + a1.y + b2[d + 1]};
    }
}

// Single row score (for the lone row 1; uniform addr, s_load is fine here)
__device__ __forceinline__ float dot_row(const float* __restrict__ row, const v2f wv[5]) {
    v2f c0 = *(const v2f*)(row + 0);
    v4f c1 = *(const v4f*)(row + 2);
    v4f c2 = *(const v4f*)(row + 6);
    v2f a = wv[0] * c0;
    a += wv[1] * c1.lo; a += wv[2] * c1.hi;
    a += wv[3] * c2.lo; a += wv[4] * c2.hi;
    return a.x + a.y;
}

// One even row-pair (rows 2p, 2p+1). tbl4 carries an opaque VGPR offset so the
// address is "divergent" -> global_load_dwordx4 (VMEM: in-order returns, vmcnt
// pipelining, VGPR-buffered) instead of scalarized s_load (OOO, lgkmcnt(0) drains).
__device__ __forceinline__ void score_pair(const v4f* tbl4, int p,
                                           const v2f wv2[5],
                                           float& best, int& bidx) {
    const v4f* tp = tbl4 + p * 5;
    v4f a0 = tp[0], a1 = tp[1], a2 = tp[2], a3 = tp[3], a4 = tp[4];
    v2f c0 = wv2[0] * a0.lo;
    c0 += wv2[1] * a0.hi; c0 += wv2[2] * a1.lo;
    c0 += wv2[3] * a1.hi; c0 += wv2[4] * a2.lo;
    float s0 = c0.x + c0.y;
    v2f c1 = wv2[0] * a2.hi;
    c1 += wv2[1] * a3.lo; c1 += wv2[2] * a3.hi;
    c1 += wv2[3] * a4.lo; c1 += wv2[4] * a4.hi;
    float s1 = c1.x + c1.y;
    float sp = s0; int ip = 2 * p;
    if (s1 > sp) { sp = s1; ip = 2 * p + 1; }   // strict > : earlier index wins ties
    if (sp > best) { best = sp; bidx = ip; }
}

__global__ __launch_bounds__(256, 2) void actor_kernel(
    const int* __restrict__ wid, const int* __restrict__ pid,
    const float* __restrict__ wemb, const float* __restrict__ pemb,
    const float* __restrict__ W1, const float* __restrict__ b1,
    const float* __restrict__ W2, const float* __restrict__ b2,
    int* __restrict__ out)
{
    __shared__ float sb[4][64];
    __shared__ int   si[4][64];

    const int tid  = threadIdx.x;
    const int lane = tid & 63;
    const int wave = tid >> 6;
    const int g    = wave >> 1;            // element group (2 groups of 64 per block)
    const int h    = wave & 1;             // row-half worker
    const int b    = blockIdx.x * 128 + g * 64 + lane;

    // Opaque zero in a VGPR: compiler must treat it as unknown & divergent,
    // defeating uniform-load scalarization for the table stream.
    unsigned zoff = 0;
    asm volatile("" : "+v"(zoff));
    const v4f* tbl4 = (const v4f*)((const char*)pemb + zoff);

    // ---- MLP (redundant across the 2 h-waves of a group; lane-identical) ----
    v2f wv2[5];
    mlp_eval(wemb + wid[b] * EMB, pemb + pid[b] * EMB, W1, b1, W2, b2, wv2);

    float best = -FLT_MAX;
    int   bidx = 1;

    // Pair range [1,1245) = rows 2..2489; COMPILE-TIME bounds per branch
    // (R5/R6 runtime bounds broke load batching). Lone row 1 -> h0.
    if (h == 0) {
        best = dot_row(pemb + 10, wv2); bidx = 1;
        #pragma unroll 4
        for (int p = 1; p < 623; ++p) score_pair(tbl4, p, wv2, best, bidx);
    } else {
        #pragma unroll 4
        for (int p = 623; p < 1245; ++p) score_pair(tbl4, p, wv2, best, bidx);
    }

    // ---- combine halves (h1 indices all higher -> strict > keeps first-max) ----
    sb[wave][lane] = best;
    si[wave][lane] = bidx;
    __syncthreads();
    if (h == 0) {
        float v  = sb[wave + 1][lane];
        int   vi = si[wave + 1][lane];
        if (v > best) { best = v; bidx = vi; }
        out[b] = bidx;
    }
}

extern "C" void kernel_launch(void* const* d_in, const int* in_sizes, int n_in,
                              void* d_out, int out_size, void* d_ws, size_t ws_size,
                              hipStream_t stream) {
    const int*   wid  = (const int*)  d_in[0];
    const int*   pid  = (const int*)  d_in[1];
    const float* wemb = (const float*)d_in[2];
    const float* pemb = (const float*)d_in[3];
    const float* W1   = (const float*)d_in[4];
    const float* b1   = (const float*)d_in[5];
    const float* W2   = (const float*)d_in[6];
    const float* b2   = (const float*)d_in[7];
    int* out = (int*)d_out;

    const int B = in_sizes[0];               // 65536
    actor_kernel<<<B / 128, 256, 0, stream>>>(wid, pid, wemb, pemb, W1, b1, W2, b2, out);
}

// Round 8
// 166.164 us; speedup vs baseline: 1.6049x; 1.5178x over previous
//
#include <hip/hip_runtime.h>
#include <float.h>

using v2f = __attribute__((ext_vector_type(2))) float;
using v4f = __attribute__((ext_vector_type(4))) float;

#define EMB 10
#define STATE 20
#define HIDDEN 40
#define NPROJ 2490

// Per-element MLP: x = [wemb[wi], pemb[pi]] -> relu(W1 x + b1) -> W2 h + b2
__device__ __forceinline__ void mlp_eval(
    const float* __restrict__ wr, const float* __restrict__ pr,
    const float* __restrict__ W1, const float* __restrict__ b1,
    const float* __restrict__ W2, const float* __restrict__ b2,
    v2f wv2[5])
{
    v2f x2[STATE / 2];
    #pragma unroll
    for (int k = 0; k < EMB / 2; ++k) x2[k] = *(const v2f*)(wr + 2 * k);
    #pragma unroll
    for (int k = 0; k < EMB / 2; ++k) x2[EMB / 2 + k] = *(const v2f*)(pr + 2 * k);

    float hb[HIDDEN];
    #pragma unroll 4
    for (int j = 0; j < HIDDEN; ++j) {       // W1/b1 block-uniform -> s_loads
        const v2f* w1r = (const v2f*)(W1 + j * STATE);
        v2f a = w1r[0] * x2[0];
        #pragma unroll
        for (int k = 1; k < STATE / 2; ++k) a += w1r[k] * x2[k];
        hb[j] = fmaxf(a.x + a.y + b1[j], 0.0f);
    }
    v2f h2[HIDDEN / 2];
    #pragma unroll
    for (int k = 0; k < HIDDEN / 2; ++k) h2[k] = (v2f){hb[2 * k], hb[2 * k + 1]};

    #pragma unroll
    for (int d = 0; d < EMB; d += 2) {
        const v2f* w2r0 = (const v2f*)(W2 + d * HIDDEN);
        const v2f* w2r1 = (const v2f*)(W2 + (d + 1) * HIDDEN);
        v2f a0 = w2r0[0] * h2[0];
        v2f a1 = w2r1[0] * h2[0];
        #pragma unroll
        for (int k = 1; k < HIDDEN / 2; ++k) { a0 += w2r0[k] * h2[k]; a1 += w2r1[k] * h2[k]; }
        wv2[d / 2] = (v2f){a0.x + a0.y + b2[d], a1.x + a1.y + b2[d + 1]};
    }
}

// Single row score (lone row 1)
__device__ __forceinline__ float dot_row(const float* __restrict__ row, const v2f wv[5]) {
    v2f c0 = *(const v2f*)(row + 0);
    v4f c1 = *(const v4f*)(row + 2);
    v4f c2 = *(const v4f*)(row + 6);
    v2f a = wv[0] * c0;
    a += wv[1] * c1.lo; a += wv[2] * c1.hi;
    a += wv[3] * c2.lo; a += wv[4] * c2.hi;
    return a.x + a.y;
}

// One even row-pair (rows 2p, 2p+1); uniform p-indexed -> s_load_dwordx4 data in
// SGPRs feeding v_pk_fma_f32. R3-proven body, do not touch.
__device__ __forceinline__ void score_pair(const v4f* __restrict__ tbl4, int p,
                                           const v2f wv2[5],
                                           float& best, int& bidx) {
    const v4f* tp = tbl4 + p * 5;
    v4f a0 = tp[0], a1 = tp[1], a2 = tp[2], a3 = tp[3], a4 = tp[4];
    v2f c0 = wv2[0] * a0.lo;
    c0 += wv2[1] * a0.hi; c0 += wv2[2] * a1.lo;
    c0 += wv2[3] * a1.hi; c0 += wv2[4] * a2.lo;
    float s0 = c0.x + c0.y;
    v2f c1 = wv2[0] * a2.hi;
    c1 += wv2[1] * a3.lo; c1 += wv2[2] * a3.hi;
    c1 += wv2[3] * a4.lo; c1 += wv2[4] * a4.hi;
    float s1 = c1.x + c1.y;
    float sp = s0; int ip = 2 * p;
    if (s1 > sp) { sp = s1; ip = 2 * p + 1; }   // strict > : earlier index wins ties
    if (sp > best) { best = sp; bidx = ip; }
}

__global__ __launch_bounds__(256, 4) void actor_kernel(
    const int* __restrict__ wid, const int* __restrict__ pid,
    const float* __restrict__ wemb, const float* __restrict__ pemb,
    const float* __restrict__ W1, const float* __restrict__ b1,
    const float* __restrict__ W2, const float* __restrict__ b2,
    int* __restrict__ out)
{
    __shared__ float sb[4][64];
    __shared__ int   si[4][64];

    const int tid  = threadIdx.x;
    const int lane = tid & 63;
    const int h    = tid >> 6;             // row-split worker 0..3
    const int b    = blockIdx.x * 64 + lane;

    const v4f* __restrict__ tbl4 = (const v4f*)__builtin_assume_aligned(pemb, 16);

    // ---- MLP (redundant across 4 waves; lane-identical inputs) ----
    v2f wv2[5];
    mlp_eval(wemb + wid[b] * EMB, pemb + pid[b] * EMB, W1, b1, W2, b2, wv2);

    float best = -FLT_MAX;
    int   bidx = 1;

    // Pair range [1,1245) = rows 2..2489, 4-way split with LITERAL bounds per
    // branch (R6's runtime plo[] destroyed s_load batching: 417 vs 162 cyc/pair).
    if (h == 0) {
        best = dot_row(pemb + 10, wv2); bidx = 1;   // lone row 1
        #pragma unroll 4
        for (int p = 1; p < 312; ++p)    score_pair(tbl4, p, wv2, best, bidx);
    } else if (h == 1) {
        #pragma unroll 4
        for (int p = 312; p < 623; ++p)  score_pair(tbl4, p, wv2, best, bidx);
    } else if (h == 2) {
        #pragma unroll 4
        for (int p = 623; p < 934; ++p)  score_pair(tbl4, p, wv2, best, bidx);
    } else {
        #pragma unroll 4
        for (int p = 934; p < 1245; ++p) score_pair(tbl4, p, wv2, best, bidx);
    }

    // ---- combine the 4 row-chunks (ascending ranges -> strict > is exact) ----
    sb[h][lane] = best;
    si[h][lane] = bidx;
    __syncthreads();
    if (h == 0) {
        #pragma unroll
        for (int k = 1; k < 4; ++k) {
            float v = sb[k][lane]; int j = si[k][lane];
            if (v > best) { best = v; bidx = j; }
        }
        out[b] = bidx;
    }
}

extern "C" void kernel_launch(void* const* d_in, const int* in_sizes, int n_in,
                              void* d_out, int out_size, void* d_ws, size_t ws_size,
                              hipStream_t stream) {
    const int*   wid  = (const int*)  d_in[0];
    const int*   pid  = (const int*)  d_in[1];
    const float* wemb = (const float*)d_in[2];
    const float* pemb = (const float*)d_in[3];
    const float* W1   = (const float*)d_in[4];
    const float* b1   = (const float*)d_in[5];
    const float* W2   = (const float*)d_in[6];
    const float* b2   = (const float*)d_in[7];
    int* out = (int*)d_out;

    const int B = in_sizes[0];               // 65536
    actor_kernel<<<B / 64, 256, 0, stream>>>(wid, pid, wemb, pemb, W1, b1, W2, b2, out);
}